// Round 19
// baseline (118.967 us; speedup 1.0000x reference)
//
#include <hip/hip_runtime.h>
#include <hip/hip_bf16.h>
#include <stdint.h>

typedef __bf16 bf16x8 __attribute__((ext_vector_type(8)));
typedef __bf16 bf16x4 __attribute__((ext_vector_type(4)));
typedef float  f32x4  __attribute__((ext_vector_type(4)));
typedef float  f32x16 __attribute__((ext_vector_type(16)));

#define GLOBAL_AS __attribute__((address_space(1)))
#define LDS_AS    __attribute__((address_space(3)))

__device__ __forceinline__ void gld_lds16(const __bf16* g, __bf16* l) {
  __builtin_amdgcn_global_load_lds((GLOBAL_AS void*)g, (LDS_AS void*)l, 16, 0, 0);
}

// q pre-scale: 1/sqrt(64) * log2(e)  (softmax runs in exp2 domain)
#define QSCALE 0.18033688011116029f

__device__ __forceinline__ unsigned pk2(float a, float b) {
  unsigned short ua = __builtin_bit_cast(unsigned short, (__bf16)a);
  unsigned short ub = __builtin_bit_cast(unsigned short, (__bf16)b);
  return (unsigned)ua | ((unsigned)ub << 16);
}

union PackU { unsigned u[4]; bf16x8 v; };

// ---------------- fused prep: cast x->bf16 + transpose-cast w_attn, w_proj ----------------
__global__ __launch_bounds__(256)
void prep_kernel(const float* __restrict__ x, __bf16* __restrict__ xb,
                 const float* __restrict__ wa, __bf16* __restrict__ waT,
                 const float* __restrict__ wp, __bf16* __restrict__ wpT)
{
  const int id = blockIdx.x;
  const int tid = threadIdx.x;
  if (id < 2048) {
    int i = (id * 256 + tid) * 8;
    float4 a = *(const float4*)(x + i);
    float4 b = *(const float4*)(x + i + 4);
    bf16x8 o;
    o[0]=(__bf16)a.x; o[1]=(__bf16)a.y; o[2]=(__bf16)a.z; o[3]=(__bf16)a.w;
    o[4]=(__bf16)b.x; o[5]=(__bf16)b.y; o[6]=(__bf16)b.z; o[7]=(__bf16)b.w;
    *(bf16x8*)(xb + i) = o;
    return;
  }
  __shared__ float tile[32][33];
  const float* src; __bf16* dst; int R, C, c0, r0;
  if (id < 5120) {
    int idx = id - 2048;
    src = wa; dst = waT; R = 1024; C = 3072;
    c0 = (idx % 96) * 32; r0 = (idx / 96) * 32;
  } else {
    int idx = id - 5120;
    src = wp; dst = wpT; R = 1024; C = 1024;
    c0 = (idx & 31) * 32; r0 = (idx >> 5) * 32;
  }
  int tx = tid & 31, ty = tid >> 5;
  #pragma unroll
  for (int i = 0; i < 32; i += 8)
    tile[ty + i][tx] = src[(size_t)(r0 + ty + i) * C + (c0 + tx)];
  __syncthreads();
  #pragma unroll
  for (int i = 0; i < 32; i += 8)
    dst[(size_t)(c0 + ty + i) * R + (r0 + tx)] = (__bf16)tile[tx][ty + i];
}

// ---------------- BMx128 bf16 GEMM, BK=64, swizzled LDS, 32x32x16 MFMA (R18, verified) ----------------
template<int MODE, int BM>
__global__ __launch_bounds__(256, (BM == 128 ? 3 : 2))
void gemm_kernel(const __bf16* __restrict__ A,
                 const __bf16* __restrict__ Bt,
                 const float*  __restrict__ bias,
                 float* __restrict__ outF,
                 __bf16* __restrict__ qb,
                 __bf16* __restrict__ kb,
                 __bf16* __restrict__ vb,
                 int M, int N, int K)
{
  __shared__ __bf16 As[BM * 64];
  __shared__ __bf16 Bs[128 * 64];
  const int tid  = threadIdx.x;
  const int wave = tid >> 6, lane = tid & 63;
  const int l31 = lane & 31, hi = lane >> 5;
  int bm, bn;
  if (MODE == 0) {
    int bid = blockIdx.x;                        // 0..767
    int bm_i = (bid & 7) * 4 + ((bid >> 3) & 3); // xcd-chunked bm
    int bn_i = bid >> 5;                         // 0..23
    bm = bm_i * 128; bn = bn_i * 128;
  } else {
    bm = blockIdx.y * BM; bn = blockIdx.x * 128;
  }
  const int wr = (wave >> 1) * (BM / 2);
  const int wc = (wave & 1) * 64;
  constexpr int MT = BM / 64;                    // 32x32 tiles per wave in M

  f32x16 acc[MT][2] = {};

  const int nkt = K >> 6;
  for (int kt = 0; kt < nkt; ++kt) {
    const int k0 = kt << 6;
    __syncthreads();
    #pragma unroll
    for (int j = 0; j < BM / 32; ++j) {
      int c = j * 256 + tid;
      int r = c >> 3, cc = c & 7;
      int cs = cc ^ (r & 7);
      gld_lds16(A + (size_t)(bm + r) * K + (k0 + cs * 8), As + c * 8);
    }
    #pragma unroll
    for (int j = 0; j < 4; ++j) {
      int c = j * 256 + tid;
      int r = c >> 3, cc = c & 7;
      int cs = cc ^ (r & 7);
      gld_lds16(Bt + (size_t)(bn + r) * K + (k0 + cs * 8), Bs + c * 8);
    }
    __syncthreads();
    #pragma unroll
    for (int kk = 0; kk < 4; ++kk) {
      bf16x8 af[MT], bfr[2];
      #pragma unroll
      for (int mt = 0; mt < MT; ++mt) {
        int row = wr + mt * 32 + l31;
        int ch = (kk * 2 + hi) ^ (row & 7);
        af[mt] = *(const bf16x8*)(As + row * 64 + ch * 8);
      }
      #pragma unroll
      for (int nt = 0; nt < 2; ++nt) {
        int row = wc + nt * 32 + l31;
        int ch = (kk * 2 + hi) ^ (row & 7);
        bfr[nt] = *(const bf16x8*)(Bs + row * 64 + ch * 8);
      }
      #pragma unroll
      for (int mt = 0; mt < MT; ++mt)
        #pragma unroll
        for (int nt = 0; nt < 2; ++nt)
          acc[mt][nt] = __builtin_amdgcn_mfma_f32_32x32x16_bf16(af[mt], bfr[nt], acc[mt][nt], 0, 0, 0);
    }
  }

  float bv[2];
  #pragma unroll
  for (int nt = 0; nt < 2; ++nt) bv[nt] = bias[bn + wc + nt * 32 + l31];

  if (MODE == 1) {
    #pragma unroll
    for (int mt = 0; mt < MT; ++mt)
      #pragma unroll
      for (int nt = 0; nt < 2; ++nt) {
        int col = bn + wc + nt * 32 + l31;
        #pragma unroll
        for (int q2 = 0; q2 < 4; ++q2) {
          int rbase = bm + wr + mt * 32 + 8 * q2 + 4 * hi;
          #pragma unroll
          for (int j = 0; j < 4; ++j)
            outF[(size_t)(rbase + j) * N + col] = acc[mt][nt][q2 * 4 + j] + bv[nt];
        }
      }
  } else {
    #pragma unroll
    for (int mt = 0; mt < MT; ++mt) {
      #pragma unroll
      for (int q2 = 0; q2 < 4; ++q2) {
        const int tbase = bm + wr + mt * 32 + 8 * q2 + 4 * hi;
        const int b = tbase >> 11, t = tbase & 2047;
        #pragma unroll
        for (int nt = 0; nt < 2; ++nt) {
          int n = bn + wc + nt * 32 + l31;
          int sel = n >> 10, hd = n & 1023;
          int h = hd >> 6, d = hd & 63;
          size_t bh = (size_t)(b * 16 + h);
          if (sel == 2) {
            bf16x4 pv;
            #pragma unroll
            for (int j = 0; j < 4; ++j) pv[j] = (__bf16)(acc[mt][nt][q2 * 4 + j] + bv[nt]);
            *(bf16x4*)(vb + (bh * 64 + d) * 2048 + t) = pv;   // v: [B,H,D,T]
          } else if (sel == 0) {
            #pragma unroll
            for (int j = 0; j < 4; ++j)
              qb[(bh * 2048 + (size_t)(t + j)) * 64 + d] =
                  (__bf16)((acc[mt][nt][q2 * 4 + j] + bv[nt]) * QSCALE);
          } else {
            #pragma unroll
            for (int j = 0; j < 4; ++j)
              kb[(bh * 2048 + (size_t)(t + j)) * 64 + d] =
                  (__bf16)(acc[mt][nt][q2 * 4 + j] + bv[nt]);
          }
        }
      }
    }
  }
}

// ---------------- causal flash attention: KVBLK=32, 16KB LDS, 8 blocks/CU ----------------
// 1024 blocks x 4 waves, uniform split-KV (R13 control flow at 32-kv granularity):
//  t<16:  strip t full (tiles 0..2t+1, FINAL y) then strip 31-t suffix (tiles 32..63-2t, PARTIAL)
//  t>=16: strip t prefix (tiles 0..31, PARTIAL)          -> every block 32-34 tiles.
// TILE = the mb<2 half of the R8-verified fragment algebra (same pi, labels, packing);
// V at t=32 uses a 2-bit chunk swizzle (same involution proof). LDS halved to 16KB ->
// __launch_bounds__(256,8): 8 blocks/CU = 32 resident waves (2x R16) to attack the
// latency plateau. Fixed-max exp2 softmax; partials are pure sums (merge = add).
__global__ __launch_bounds__(256, 8)
void attn_kernel(const __bf16* __restrict__ qg_, const __bf16* __restrict__ kg,
                 const __bf16* __restrict__ vg, __bf16* __restrict__ yg,
                 __bf16* __restrict__ pY, float* __restrict__ pL)
{
  const int n = blockIdx.x;
  const int xcd = n & 7;
  const int m = n >> 3;              // 0..127
  const int bh = xcd + 8 * (m & 3);
  const int t = m >> 2;              // chunk id 0..31
  const int b = bh >> 4, h = bh & 15;

  const int tid  = threadIdx.x;
  const int wave = tid >> 6;
  const int lane = tid & 63;
  const int l15  = lane & 15;
  const int g    = lane >> 4;
  const int sw   = l15 & 7;

  __shared__ __bf16 Kb[2][32 * 64];  // [mu][d]: row mu holds K row pi(mu); chunk-swizzled
  __shared__ __bf16 Vb[2][64 * 32];  // [d][t]: 2-bit chunk-swizzled

  const __bf16* qbase = qg_ + (size_t)bh * 2048 * 64;
  const __bf16* kbase = kg  + (size_t)bh * 2048 * 64;
  const __bf16* vbase = vg  + (size_t)bh * 64 * 2048;

  bf16x8 qf0, qf1;
  f32x4 o0, o1, o2, o3, osum;

  bf16x8 ones;
  #pragma unroll
  for (int j = 0; j < 8; ++j) ones[j] = (__bf16)1.0f;

  auto LOADQ = [&](int strip) {
    const int q16 = strip * 64 + wave * 16 + l15;
    qf0 = *(const bf16x8*)(qbase + (size_t)q16 * 64 + g * 8);
    qf1 = *(const bf16x8*)(qbase + (size_t)q16 * 64 + 32 + g * 8);
  };
  auto RESET = [&]() {
    o0 = f32x4{}; o1 = f32x4{}; o2 = f32x4{}; o3 = f32x4{}; osum = f32x4{};
  };
  auto STAGE = [&](int kt, int bsel) {   // kt = 32-kv tile index (0..63)
    int c = tid;                          // 256 K-chunks
    int cr = c >> 3, cc = c & 7;
    int cs = cc ^ (cr & 7);
    int pr = (cr & 3) | ((cr & 0x10) >> 2) | ((cr & 0x0C) << 1);  // pi (5-bit)
    gld_lds16(kbase + (size_t)(kt * 32 + pr) * 64 + cs * 8, &Kb[bsel][0] + c * 8);
    int d = c >> 2, sl = c & 3;           // 256 V-chunks (64 rows x 4)
    int cs2 = sl ^ (d & 3);
    gld_lds16(vbase + (size_t)d * 2048 + kt * 32 + cs2 * 8, &Vb[bsel][0] + c * 8);
  };

  // dg: 0 = no mask, 1 = lower diag tile (labels 0..31), 2 = upper (labels 32..63)
  auto TILE = [&](int cur, int dg) {
    const __bf16* KL = &Kb[cur][0];
    f32x4 s0 = {}, s1 = {};
    bf16x8 k00 = *(const bf16x8*)(KL + (0  + l15) * 64 + ((0 + g) ^ sw) * 8);
    bf16x8 k01 = *(const bf16x8*)(KL + (0  + l15) * 64 + ((4 + g) ^ sw) * 8);
    bf16x8 k10 = *(const bf16x8*)(KL + (16 + l15) * 64 + ((0 + g) ^ sw) * 8);
    bf16x8 k11 = *(const bf16x8*)(KL + (16 + l15) * 64 + ((4 + g) ^ sw) * 8);
    __builtin_amdgcn_s_setprio(1);
    s0 = __builtin_amdgcn_mfma_f32_16x16x32_bf16(k00, qf0, s0, 0, 0, 0);
    s0 = __builtin_amdgcn_mfma_f32_16x16x32_bf16(k01, qf1, s0, 0, 0, 0);
    s1 = __builtin_amdgcn_mfma_f32_16x16x32_bf16(k10, qf0, s1, 0, 0, 0);
    s1 = __builtin_amdgcn_mfma_f32_16x16x32_bf16(k11, qf1, s1, 0, 0, 0);
    __builtin_amdgcn_s_setprio(0);

    if (dg) {
      const int off = (dg == 2) ? 32 : 0;
      const int qr = wave * 16 + l15;
      #pragma unroll
      for (int r2 = 0; r2 < 4; ++r2) {
        if (off + 8 * g + r2     > qr) s0[r2] = -3.0e38f;
        if (off + 8 * g + 4 + r2 > qr) s1[r2] = -3.0e38f;
      }
    }

    #pragma unroll
    for (int r2 = 0; r2 < 4; ++r2) { s0[r2] = exp2f(s0[r2]); s1[r2] = exp2f(s1[r2]); }

    PackU pa;
    pa.u[0] = pk2(s0[0], s0[1]); pa.u[1] = pk2(s0[2], s0[3]);
    pa.u[2] = pk2(s1[0], s1[1]); pa.u[3] = pk2(s1[2], s1[3]);

    const __bf16* VL = &Vb[cur][0];
    const int vc = (g ^ (l15 & 3)) * 8;
    bf16x8 v0 = *(const bf16x8*)(VL + (0  + l15) * 32 + vc);
    bf16x8 v1 = *(const bf16x8*)(VL + (16 + l15) * 32 + vc);
    bf16x8 v2 = *(const bf16x8*)(VL + (32 + l15) * 32 + vc);
    bf16x8 v3 = *(const bf16x8*)(VL + (48 + l15) * 32 + vc);

    __builtin_amdgcn_s_setprio(1);
    osum = __builtin_amdgcn_mfma_f32_16x16x32_bf16(pa.v, ones, osum, 0, 0, 0);
    o0 = __builtin_amdgcn_mfma_f32_16x16x32_bf16(pa.v, v0, o0, 0, 0, 0);
    o1 = __builtin_amdgcn_mfma_f32_16x16x32_bf16(pa.v, v1, o1, 0, 0, 0);
    o2 = __builtin_amdgcn_mfma_f32_16x16x32_bf16(pa.v, v2, o2, 0, 0, 0);
    o3 = __builtin_amdgcn_mfma_f32_16x16x32_bf16(pa.v, v3, o3, 0, 0, 0);
    __builtin_amdgcn_s_setprio(0);
  };

  auto WRITE_Y = [&](int strip) {
    #pragma unroll
    for (int r2 = 0; r2 < 4; ++r2) {
      float il = 1.0f / osum[r2];
      int trow = strip * 64 + wave * 16 + 4 * g + r2;
      __bf16* dst = yg + ((size_t)(b * 2048 + trow)) * 1024 + h * 64;
      dst[l15]      = (__bf16)(o0[r2] * il);
      dst[16 + l15] = (__bf16)(o1[r2] * il);
      dst[32 + l15] = (__bf16)(o2[r2] * il);
      dst[48 + l15] = (__bf16)(o3[r2] * il);
    }
  };
  auto WRITE_PART = [&](int slot) {
    __bf16* po = pY + (size_t)slot * 4096;
    #pragma unroll
    for (int r2 = 0; r2 < 4; ++r2) {
      int row = wave * 16 + 4 * g + r2;
      __bf16* dst = po + row * 64;
      dst[l15]      = (__bf16)o0[r2];
      dst[16 + l15] = (__bf16)o1[r2];
      dst[32 + l15] = (__bf16)o2[r2];
      dst[48 + l15] = (__bf16)o3[r2];
    }
    if (l15 == 0) {
      #pragma unroll
      for (int r2 = 0; r2 < 4; ++r2)
        pL[slot * 64 + wave * 16 + 4 * g + r2] = osum[r2];
    }
  };

  int cur = 0;
  if (t < 16) {
    const int sB = 31 - t;
    const int nA = 2 * t + 2;            // phase-A tiles; phase B: 32..63-2t (32-2t tiles)
    auto kvn = [&](int j) { return (j < nA) ? j : (32 + j - nA); };
    LOADQ(t); RESET();
    STAGE(kvn(0), 0);
    for (int j = 0; j < 34; ++j) {
      __syncthreads();
      if (j < 33) STAGE(kvn(j + 1), cur ^ 1);
      const int jj = kvn(j);
      int dg = 0;
      if (j < nA) { if (jj == 2 * t) dg = 1; else if (jj == 2 * t + 1) dg = 2; }
      else        { if (jj == 2 * sB) dg = 1; else if (jj == 2 * sB + 1) dg = 2; }
      if (!(dg == 2 && wave < 2)) TILE(cur, dg);   // upper diag fully masked for waves 0,1
      if (j == nA - 1) { WRITE_Y(t); LOADQ(sB); RESET(); }
      cur ^= 1;
    }
    WRITE_PART((bh * 16 + (15 - t)) * 2 + 1);      // suffix of strip 31-t
  } else {
    LOADQ(t); RESET();
    STAGE(0, 0);
    for (int j = 0; j < 32; ++j) {
      __syncthreads();
      if (j < 31) STAGE(j + 1, cur ^ 1);
      TILE(cur, 0);
      cur ^= 1;
    }
    WRITE_PART((bh * 16 + (t - 16)) * 2);          // prefix of strip t
  }
}

// ---------------- merge: y = (Oa + Ob) / (la + lb) for split strips (R13, verified) ----------------
__global__ __launch_bounds__(256)
void attn_merge_kernel(const __bf16* __restrict__ pY, const float* __restrict__ pL,
                       __bf16* __restrict__ yg)
{
  const int us = blockIdx.x & 15, bh = blockIdx.x >> 4;
  const int b = bh >> 4, h = bh & 15;
  const int tid = threadIdx.x;
  const int row = tid >> 2, d0 = (tid & 3) * 16;
  const int slotA = (bh * 16 + us) * 2, slotB = slotA + 1;

  float l = pL[slotA * 64 + row] + pL[slotB * 64 + row];
  float inv = 1.0f / l;

  const __bf16* pa = pY + (size_t)slotA * 4096 + row * 64 + d0;
  const __bf16* pb = pY + (size_t)slotB * 4096 + row * 64 + d0;
  __bf16* dst = yg + ((size_t)(b * 2048 + (16 + us) * 64 + row)) * 1024 + h * 64 + d0;

  bf16x8 a0 = *(const bf16x8*)pa, a1 = *(const bf16x8*)(pa + 8);
  bf16x8 b0 = *(const bf16x8*)pb, b1 = *(const bf16x8*)(pb + 8);
  bf16x8 r0, r1;
  #pragma unroll
  for (int j = 0; j < 8; ++j) {
    r0[j] = (__bf16)(((float)a0[j] + (float)b0[j]) * inv);
    r1[j] = (__bf16)(((float)a1[j] + (float)b1[j]) * inv);
  }
  *(bf16x8*)dst = r0;
  *(bf16x8*)(dst + 8) = r1;
}

extern "C" void kernel_launch(void* const* d_in, const int* in_sizes, int n_in,
                              void* d_out, int out_size, void* d_ws, size_t ws_size,
                              hipStream_t stream)
{
  const float* x      = (const float*)d_in[0];
  const float* w_attn = (const float*)d_in[1];
  const float* b_attn = (const float*)d_in[2];
  const float* w_proj = (const float*)d_in[3];
  const float* b_proj = (const float*)d_in[4];
  float* out = (float*)d_out;

  __bf16* xb  = (__bf16*)d_ws;                      // [4096,1024]
  __bf16* waT = xb  + (size_t)4096 * 1024;          // [3072,1024]  (w_attn^T)
  __bf16* wpT = waT + (size_t)3072 * 1024;          // [1024,1024]  (w_proj^T)
  __bf16* qb  = wpT + (size_t)1024 * 1024;          // [B,H,T,D] (pre-scaled)
  __bf16* kb  = qb  + (size_t)32 * 2048 * 64;       // [B,H,T,D]
  __bf16* vb  = kb  + (size_t)32 * 2048 * 64;       // [B,H,D,T]
  __bf16* yb  = vb  + (size_t)32 * 2048 * 64;       // [4096,1024]

  // partials alias regions dead after gemm0: pY = xb (exact fit), pL in waT
  __bf16* pY = xb;                                  // 1024 slots x [64][64] bf16
  float*  pL = (float*)waT;                         // 1024 x 64 f32

  prep_kernel<<<6144, 256, 0, stream>>>(x, xb, w_attn, waT, w_proj, wpT);
  gemm_kernel<0, 128><<<768, 256, 0, stream>>>(xb, waT, b_attn, nullptr,
                                               qb, kb, vb, 4096, 3072, 1024);
  attn_kernel<<<1024, 256, 0, stream>>>(qb, kb, vb, yb, pY, pL);
  attn_merge_kernel<<<512, 256, 0, stream>>>(pY, pL, yb);
  gemm_kernel<1, 64><<<dim3(8, 64), 256, 0, stream>>>(yb, wpT, b_proj, out,
                                                      nullptr, nullptr, nullptr, 4096, 1024, 1024);
}

// Round 20
// 95.650 us; speedup vs baseline: 1.2438x; 1.2438x over previous
//
#include <hip/hip_runtime.h>
#include <hip/hip_bf16.h>
#include <stdint.h>

typedef __bf16 bf16x8 __attribute__((ext_vector_type(8)));
typedef __bf16 bf16x4 __attribute__((ext_vector_type(4)));
typedef float  f32x4  __attribute__((ext_vector_type(4)));

#define GLOBAL_AS __attribute__((address_space(1)))
#define LDS_AS    __attribute__((address_space(3)))

__device__ __forceinline__ void gld_lds16(const __bf16* g, __bf16* l) {
  __builtin_amdgcn_global_load_lds((GLOBAL_AS void*)g, (LDS_AS void*)l, 16, 0, 0);
}

// q pre-scale: 1/sqrt(64) * log2(e)  (softmax runs in exp2 domain)
#define QSCALE 0.18033688011116029f

__device__ __forceinline__ unsigned pk2(float a, float b) {
  unsigned short ua = __builtin_bit_cast(unsigned short, (__bf16)a);
  unsigned short ub = __builtin_bit_cast(unsigned short, (__bf16)b);
  return (unsigned)ua | ((unsigned)ub << 16);
}

union PackU { unsigned u[4]; bf16x8 v; };

// ---------------- fused prep: cast x->bf16 + transpose-cast w_attn, w_proj ----------------
__global__ __launch_bounds__(256)
void prep_kernel(const float* __restrict__ x, __bf16* __restrict__ xb,
                 const float* __restrict__ wa, __bf16* __restrict__ waT,
                 const float* __restrict__ wp, __bf16* __restrict__ wpT)
{
  const int id = blockIdx.x;
  const int tid = threadIdx.x;
  if (id < 2048) {
    int i = (id * 256 + tid) * 8;
    float4 a = *(const float4*)(x + i);
    float4 b = *(const float4*)(x + i + 4);
    bf16x8 o;
    o[0]=(__bf16)a.x; o[1]=(__bf16)a.y; o[2]=(__bf16)a.z; o[3]=(__bf16)a.w;
    o[4]=(__bf16)b.x; o[5]=(__bf16)b.y; o[6]=(__bf16)b.z; o[7]=(__bf16)b.w;
    *(bf16x8*)(xb + i) = o;
    return;
  }
  __shared__ float tile[32][33];
  const float* src; __bf16* dst; int R, C, c0, r0;
  if (id < 5120) {
    int idx = id - 2048;
    src = wa; dst = waT; R = 1024; C = 3072;
    c0 = (idx % 96) * 32; r0 = (idx / 96) * 32;
  } else {
    int idx = id - 5120;
    src = wp; dst = wpT; R = 1024; C = 1024;
    c0 = (idx & 31) * 32; r0 = (idx >> 5) * 32;
  }
  int tx = tid & 31, ty = tid >> 5;
  #pragma unroll
  for (int i = 0; i < 32; i += 8)
    tile[ty + i][tx] = src[(size_t)(r0 + ty + i) * C + (c0 + tx)];
  __syncthreads();
  #pragma unroll
  for (int i = 0; i < 32; i += 8)
    dst[(size_t)(c0 + ty + i) * R + (r0 + tx)] = (__bf16)tile[tx][ty + i];
}

// ---------------- BMx128 bf16 GEMM, BK=64, swizzled LDS (verified R10/R13) ----------------
template<int MODE, int BM>
__global__ __launch_bounds__(256, (BM == 128 ? 3 : 2))
void gemm_kernel(const __bf16* __restrict__ A,
                 const __bf16* __restrict__ Bt,
                 const float*  __restrict__ bias,
                 float* __restrict__ outF,
                 __bf16* __restrict__ qb,
                 __bf16* __restrict__ kb,
                 __bf16* __restrict__ vb,
                 int M, int N, int K)
{
  __shared__ __bf16 As[BM * 64];
  __shared__ __bf16 Bs[128 * 64];
  const int tid  = threadIdx.x;
  const int wave = tid >> 6, lane = tid & 63;
  const int lo = lane & 15, g4 = lane >> 4;
  int bm, bn;
  if (MODE == 0) {
    int bid = blockIdx.x;                        // 0..767
    int bm_i = (bid & 7) * 4 + ((bid >> 3) & 3); // xcd-chunked bm
    int bn_i = bid >> 5;                         // 0..23
    bm = bm_i * 128; bn = bn_i * 128;
  } else {
    bm = blockIdx.y * BM; bn = blockIdx.x * 128;
  }
  const int wr = (wave >> 1) * (BM / 2);
  const int wc = (wave & 1) * 64;
  constexpr int MF = BM / 32;

  f32x4 acc[MF][4] = {};

  const int nkt = K >> 6;
  for (int kt = 0; kt < nkt; ++kt) {
    const int k0 = kt << 6;
    __syncthreads();
    #pragma unroll
    for (int j = 0; j < BM / 32; ++j) {
      int c = j * 256 + tid;
      int r = c >> 3, cc = c & 7;
      int cs = cc ^ (r & 7);
      gld_lds16(A + (size_t)(bm + r) * K + (k0 + cs * 8), As + c * 8);
    }
    #pragma unroll
    for (int j = 0; j < 4; ++j) {
      int c = j * 256 + tid;
      int r = c >> 3, cc = c & 7;
      int cs = cc ^ (r & 7);
      gld_lds16(Bt + (size_t)(bn + r) * K + (k0 + cs * 8), Bs + c * 8);
    }
    __syncthreads();
    #pragma unroll
    for (int ks = 0; ks < 2; ++ks) {
      bf16x8 af[MF], bfr[4];
      #pragma unroll
      for (int mf = 0; mf < MF; ++mf) {
        int row = wr + mf * 16 + lo;
        int ch = (ks * 4 + g4) ^ (row & 7);
        af[mf] = *(const bf16x8*)(As + row * 64 + ch * 8);
      }
      #pragma unroll
      for (int nf = 0; nf < 4; ++nf) {
        int row = wc + nf * 16 + lo;
        int ch = (ks * 4 + g4) ^ (row & 7);
        bfr[nf] = *(const bf16x8*)(Bs + row * 64 + ch * 8);
      }
      #pragma unroll
      for (int mf = 0; mf < MF; ++mf)
        #pragma unroll
        for (int nf = 0; nf < 4; ++nf)
          acc[mf][nf] = __builtin_amdgcn_mfma_f32_16x16x32_bf16(af[mf], bfr[nf], acc[mf][nf], 0, 0, 0);
    }
  }

  float bv[4];
  #pragma unroll
  for (int nf = 0; nf < 4; ++nf) bv[nf] = bias[bn + wc + nf * 16 + lo];

  if (MODE == 1) {
    #pragma unroll
    for (int mf = 0; mf < MF; ++mf)
      #pragma unroll
      for (int nf = 0; nf < 4; ++nf) {
        int col = bn + wc + nf * 16 + lo;
        #pragma unroll
        for (int j = 0; j < 4; ++j) {
          int row = bm + wr + mf * 16 + g4 * 4 + j;
          outF[(size_t)row * N + col] = acc[mf][nf][j] + bv[nf];
        }
      }
  } else {
    #pragma unroll
    for (int mf = 0; mf < MF; ++mf) {
      const int tbase = bm + wr + mf * 16 + g4 * 4;
      const int b = tbase >> 11, t = tbase & 2047;
      #pragma unroll
      for (int nf = 0; nf < 4; ++nf) {
        int n = bn + wc + nf * 16 + lo;
        int sel = n >> 10, hd = n & 1023;
        int h = hd >> 6, d = hd & 63;
        size_t bh = (size_t)(b * 16 + h);
        if (sel == 2) {
          bf16x4 pv;
          #pragma unroll
          for (int j = 0; j < 4; ++j) pv[j] = (__bf16)(acc[mf][nf][j] + bv[nf]);
          *(bf16x4*)(vb + (bh * 64 + d) * 2048 + t) = pv;   // v: [B,H,D,T]
        } else if (sel == 0) {
          #pragma unroll
          for (int j = 0; j < 4; ++j)
            qb[(bh * 2048 + (size_t)(t + j)) * 64 + d] = (__bf16)((acc[mf][nf][j] + bv[nf]) * QSCALE);
        } else {
          #pragma unroll
          for (int j = 0; j < 4; ++j)
            kb[(bh * 2048 + (size_t)(t + j)) * 64 + d] = (__bf16)(acc[mf][nf][j] + bv[nf]);
        }
      }
    }
  }
}

// ---------------- causal flash attention: uniform split-KV (R16 verified, 42.2us) ----------------
__global__ __launch_bounds__(256, 4)
void attn_kernel(const __bf16* __restrict__ qg_, const __bf16* __restrict__ kg,
                 const __bf16* __restrict__ vg, __bf16* __restrict__ yg,
                 __bf16* __restrict__ pY, float* __restrict__ pL)
{
  const int n = blockIdx.x;
  const int xcd = n & 7;
  const int m = n >> 3;              // 0..127
  const int bh = xcd + 8 * (m & 3);
  const int t = m >> 2;              // chunk id 0..31
  const int b = bh >> 4, h = bh & 15;

  const int tid  = threadIdx.x;
  const int wave = tid >> 6;
  const int lane = tid & 63;
  const int l15  = lane & 15;
  const int g    = lane >> 4;
  const int sw   = l15 & 7;

  __shared__ __bf16 Kb[2][64 * 64];  // [mu][d]: row mu holds K row pi(mu); chunk-swizzled
  __shared__ __bf16 Vb[2][64 * 64];  // [d][t]: chunk-swizzled

  const __bf16* qbase = qg_ + (size_t)bh * 2048 * 64;
  const __bf16* kbase = kg  + (size_t)bh * 2048 * 64;
  const __bf16* vbase = vg  + (size_t)bh * 64 * 2048;

  bf16x8 qf0, qf1;
  f32x4 o0, o1, o2, o3, osum;

  bf16x8 ones;
  #pragma unroll
  for (int j = 0; j < 8; ++j) ones[j] = (__bf16)1.0f;

  auto LOADQ = [&](int strip) {
    const int q16 = strip * 64 + wave * 16 + l15;
    qf0 = *(const bf16x8*)(qbase + (size_t)q16 * 64 + g * 8);
    qf1 = *(const bf16x8*)(qbase + (size_t)q16 * 64 + 32 + g * 8);
  };
  auto RESET = [&]() {
    o0 = f32x4{}; o1 = f32x4{}; o2 = f32x4{}; o3 = f32x4{}; osum = f32x4{};
  };
  auto STAGE = [&](int kt, int bsel) {
    #pragma unroll
    for (int j = 0; j < 2; ++j) {
      int c = j * 256 + tid;
      int cr = c >> 3, cc = c & 7;
      int cs = cc ^ (cr & 7);
      int pr = (cr & 0x23) | ((cr & 0x10) >> 2) | ((cr & 0x0C) << 1);  // pi(cr)
      gld_lds16(kbase + (size_t)(kt * 64 + pr) * 64 + cs * 8, &Kb[bsel][0] + c * 8);
      gld_lds16(vbase + (size_t)cr * 2048 + (kt * 64 + cs * 8), &Vb[bsel][0] + c * 8);
    }
  };

  auto TILE = [&](int cur, bool diag) {
    const __bf16* KL = &Kb[cur][0];
    f32x4 s0 = {}, s1 = {}, s2 = {}, s3 = {};
    {
      bf16x8 k00 = *(const bf16x8*)(KL + (0  + l15) * 64 + ((0 + g) ^ sw) * 8);
      bf16x8 k01 = *(const bf16x8*)(KL + (0  + l15) * 64 + ((4 + g) ^ sw) * 8);
      bf16x8 k10 = *(const bf16x8*)(KL + (16 + l15) * 64 + ((0 + g) ^ sw) * 8);
      bf16x8 k11 = *(const bf16x8*)(KL + (16 + l15) * 64 + ((4 + g) ^ sw) * 8);
      bf16x8 k20 = *(const bf16x8*)(KL + (32 + l15) * 64 + ((0 + g) ^ sw) * 8);
      bf16x8 k21 = *(const bf16x8*)(KL + (32 + l15) * 64 + ((4 + g) ^ sw) * 8);
      bf16x8 k30 = *(const bf16x8*)(KL + (48 + l15) * 64 + ((0 + g) ^ sw) * 8);
      bf16x8 k31 = *(const bf16x8*)(KL + (48 + l15) * 64 + ((4 + g) ^ sw) * 8);
      __builtin_amdgcn_s_setprio(1);
      s0 = __builtin_amdgcn_mfma_f32_16x16x32_bf16(k00, qf0, s0, 0, 0, 0);
      s0 = __builtin_amdgcn_mfma_f32_16x16x32_bf16(k01, qf1, s0, 0, 0, 0);
      s1 = __builtin_amdgcn_mfma_f32_16x16x32_bf16(k10, qf0, s1, 0, 0, 0);
      s1 = __builtin_amdgcn_mfma_f32_16x16x32_bf16(k11, qf1, s1, 0, 0, 0);
      s2 = __builtin_amdgcn_mfma_f32_16x16x32_bf16(k20, qf0, s2, 0, 0, 0);
      s2 = __builtin_amdgcn_mfma_f32_16x16x32_bf16(k21, qf1, s2, 0, 0, 0);
      s3 = __builtin_amdgcn_mfma_f32_16x16x32_bf16(k30, qf0, s3, 0, 0, 0);
      s3 = __builtin_amdgcn_mfma_f32_16x16x32_bf16(k31, qf1, s3, 0, 0, 0);
      __builtin_amdgcn_s_setprio(0);
    }

    if (diag) {                        // causal mask (pi-mapped kv)
      const int qr = wave * 16 + l15;
      #pragma unroll
      for (int r2 = 0; r2 < 4; ++r2) {
        if (8 * g + r2          > qr) s0[r2] = -3.0e38f;
        if (8 * g + 4 + r2      > qr) s1[r2] = -3.0e38f;
        if (32 + 8 * g + r2     > qr) s2[r2] = -3.0e38f;
        if (32 + 8 * g + 4 + r2 > qr) s3[r2] = -3.0e38f;
      }
    }

    #pragma unroll
    for (int r2 = 0; r2 < 4; ++r2) s0[r2] = exp2f(s0[r2]);
    #pragma unroll
    for (int r2 = 0; r2 < 4; ++r2) s1[r2] = exp2f(s1[r2]);
    #pragma unroll
    for (int r2 = 0; r2 < 4; ++r2) s2[r2] = exp2f(s2[r2]);
    #pragma unroll
    for (int r2 = 0; r2 < 4; ++r2) s3[r2] = exp2f(s3[r2]);

    PackU pa0, pa1;
    pa0.u[0] = pk2(s0[0], s0[1]); pa0.u[1] = pk2(s0[2], s0[3]);
    pa0.u[2] = pk2(s1[0], s1[1]); pa0.u[3] = pk2(s1[2], s1[3]);
    pa1.u[0] = pk2(s2[0], s2[1]); pa1.u[1] = pk2(s2[2], s2[3]);
    pa1.u[2] = pk2(s3[0], s3[1]); pa1.u[3] = pk2(s3[2], s3[3]);

    const __bf16* VL = &Vb[cur][0];
    bf16x8 v00 = *(const bf16x8*)(VL + (0  + l15) * 64 + ((0 + g) ^ sw) * 8);
    bf16x8 v01 = *(const bf16x8*)(VL + (0  + l15) * 64 + ((4 + g) ^ sw) * 8);
    bf16x8 v10 = *(const bf16x8*)(VL + (16 + l15) * 64 + ((0 + g) ^ sw) * 8);
    bf16x8 v11 = *(const bf16x8*)(VL + (16 + l15) * 64 + ((4 + g) ^ sw) * 8);
    bf16x8 v20 = *(const bf16x8*)(VL + (32 + l15) * 64 + ((0 + g) ^ sw) * 8);
    bf16x8 v21 = *(const bf16x8*)(VL + (32 + l15) * 64 + ((4 + g) ^ sw) * 8);
    bf16x8 v30 = *(const bf16x8*)(VL + (48 + l15) * 64 + ((0 + g) ^ sw) * 8);
    bf16x8 v31 = *(const bf16x8*)(VL + (48 + l15) * 64 + ((4 + g) ^ sw) * 8);

    __builtin_amdgcn_s_setprio(1);
    osum = __builtin_amdgcn_mfma_f32_16x16x32_bf16(pa0.v, ones, osum, 0, 0, 0);
    osum = __builtin_amdgcn_mfma_f32_16x16x32_bf16(pa1.v, ones, osum, 0, 0, 0);
    o0 = __builtin_amdgcn_mfma_f32_16x16x32_bf16(pa0.v, v00, o0, 0, 0, 0);
    o0 = __builtin_amdgcn_mfma_f32_16x16x32_bf16(pa1.v, v01, o0, 0, 0, 0);
    o1 = __builtin_amdgcn_mfma_f32_16x16x32_bf16(pa0.v, v10, o1, 0, 0, 0);
    o1 = __builtin_amdgcn_mfma_f32_16x16x32_bf16(pa1.v, v11, o1, 0, 0, 0);
    o2 = __builtin_amdgcn_mfma_f32_16x16x32_bf16(pa0.v, v20, o2, 0, 0, 0);
    o2 = __builtin_amdgcn_mfma_f32_16x16x32_bf16(pa1.v, v21, o2, 0, 0, 0);
    o3 = __builtin_amdgcn_mfma_f32_16x16x32_bf16(pa0.v, v30, o3, 0, 0, 0);
    o3 = __builtin_amdgcn_mfma_f32_16x16x32_bf16(pa1.v, v31, o3, 0, 0, 0);
    __builtin_amdgcn_s_setprio(0);
  };

  auto WRITE_Y = [&](int strip) {
    #pragma unroll
    for (int r2 = 0; r2 < 4; ++r2) {
      float il = 1.0f / osum[r2];
      int trow = strip * 64 + wave * 16 + 4 * g + r2;
      __bf16* dst = yg + ((size_t)(b * 2048 + trow)) * 1024 + h * 64;
      dst[l15]      = (__bf16)(o0[r2] * il);
      dst[16 + l15] = (__bf16)(o1[r2] * il);
      dst[32 + l15] = (__bf16)(o2[r2] * il);
      dst[48 + l15] = (__bf16)(o3[r2] * il);
    }
  };
  auto WRITE_PART = [&](int slot) {
    __bf16* po = pY + (size_t)slot * 4096;
    #pragma unroll
    for (int r2 = 0; r2 < 4; ++r2) {
      int row = wave * 16 + 4 * g + r2;
      __bf16* dst = po + row * 64;
      dst[l15]      = (__bf16)o0[r2];
      dst[16 + l15] = (__bf16)o1[r2];
      dst[32 + l15] = (__bf16)o2[r2];
      dst[48 + l15] = (__bf16)o3[r2];
    }
    if (l15 == 0) {
      #pragma unroll
      for (int r2 = 0; r2 < 4; ++r2)
        pL[slot * 64 + wave * 16 + 4 * g + r2] = osum[r2];
    }
  };

  int cur = 0;
  if (t < 16) {
    LOADQ(t); RESET();
    bf16x8 qB0, qB1;   // phase-B Q prefetch
    {
      const int q16b = (31 - t) * 64 + wave * 16 + l15;
      qB0 = *(const bf16x8*)(qbase + (size_t)q16b * 64 + g * 8);
      qB1 = *(const bf16x8*)(qbase + (size_t)q16b * 64 + 32 + g * 8);
    }
    STAGE(0, 0);
    for (int j = 0; j < 17; ++j) {
      __syncthreads();
      if (j < 16) {
        int nx = j + 1;
        STAGE((nx <= t) ? nx : (nx + 15 - t), cur ^ 1);
      }
      if (j <= t) {
        TILE(cur, j == t);
        if (j == t) { WRITE_Y(t); qf0 = qB0; qf1 = qB1; RESET(); }
      } else {
        TILE(cur, j == 16);
      }
      cur ^= 1;
    }
    WRITE_PART((bh * 16 + (15 - t)) * 2 + 1);   // suffix of strip 31-t
  } else {
    LOADQ(t); RESET();
    STAGE(0, 0);
    for (int j = 0; j < 16; ++j) {
      __syncthreads();
      if (j < 15) STAGE(j + 1, cur ^ 1);
      TILE(cur, false);
      cur ^= 1;
    }
    WRITE_PART((bh * 16 + (t - 16)) * 2);       // prefix of strip t
  }
}

// ---------------- merge: y = (Oa + Ob) / (la + lb) for split strips (verified) ----------------
__global__ __launch_bounds__(256)
void attn_merge_kernel(const __bf16* __restrict__ pY, const float* __restrict__ pL,
                       __bf16* __restrict__ yg)
{
  const int us = blockIdx.x & 15, bh = blockIdx.x >> 4;
  const int b = bh >> 4, h = bh & 15;
  const int tid = threadIdx.x;
  const int row = tid >> 2, d0 = (tid & 3) * 16;
  const int slotA = (bh * 16 + us) * 2, slotB = slotA + 1;

  float l = pL[slotA * 64 + row] + pL[slotB * 64 + row];
  float inv = 1.0f / l;

  const __bf16* pa = pY + (size_t)slotA * 4096 + row * 64 + d0;
  const __bf16* pb = pY + (size_t)slotB * 4096 + row * 64 + d0;
  __bf16* dst = yg + ((size_t)(b * 2048 + (16 + us) * 64 + row)) * 1024 + h * 64 + d0;

  bf16x8 a0 = *(const bf16x8*)pa, a1 = *(const bf16x8*)(pa + 8);
  bf16x8 b0 = *(const bf16x8*)pb, b1 = *(const bf16x8*)(pb + 8);
  bf16x8 r0, r1;
  #pragma unroll
  for (int j = 0; j < 8; ++j) {
    r0[j] = (__bf16)(((float)a0[j] + (float)b0[j]) * inv);
    r1[j] = (__bf16)(((float)a1[j] + (float)b1[j]) * inv);
  }
  *(bf16x8*)dst = r0;
  *(bf16x8*)(dst + 8) = r1;
}

extern "C" void kernel_launch(void* const* d_in, const int* in_sizes, int n_in,
                              void* d_out, int out_size, void* d_ws, size_t ws_size,
                              hipStream_t stream)
{
  const float* x      = (const float*)d_in[0];
  const float* w_attn = (const float*)d_in[1];
  const float* b_attn = (const float*)d_in[2];
  const float* w_proj = (const float*)d_in[3];
  const float* b_proj = (const float*)d_in[4];
  float* out = (float*)d_out;

  __bf16* xb  = (__bf16*)d_ws;                      // [4096,1024]
  __bf16* waT = xb  + (size_t)4096 * 1024;          // [3072,1024]  (w_attn^T)
  __bf16* wpT = waT + (size_t)3072 * 1024;          // [1024,1024]  (w_proj^T)
  __bf16* qb  = wpT + (size_t)1024 * 1024;          // [B,H,T,D] (pre-scaled)
  __bf16* kb  = qb  + (size_t)32 * 2048 * 64;       // [B,H,T,D]
  __bf16* vb  = kb  + (size_t)32 * 2048 * 64;       // [B,H,D,T]
  __bf16* yb  = vb  + (size_t)32 * 2048 * 64;       // [4096,1024]

  // partials alias regions dead after gemm0: pY = xb (exact fit), pL in waT
  __bf16* pY = xb;                                  // 1024 slots x [64][64] bf16
  float*  pL = (float*)waT;                         // 1024 x 64 f32

  prep_kernel<<<6144, 256, 0, stream>>>(x, xb, w_attn, waT, w_proj, wpT);
  gemm_kernel<0, 128><<<768, 256, 0, stream>>>(xb, waT, b_attn, nullptr,
                                               qb, kb, vb, 4096, 3072, 1024);
  attn_kernel<<<1024, 256, 0, stream>>>(qb, kb, vb, yb, pY, pL);
  attn_merge_kernel<<<512, 256, 0, stream>>>(pY, pL, yb);
  gemm_kernel<1, 64><<<dim3(8, 64), 256, 0, stream>>>(yb, wpT, b_proj, out,
                                                      nullptr, nullptr, nullptr, 4096, 1024, 1024);
}